// Round 1
// baseline (1514.877 us; speedup 1.0000x reference)
//
#include <hip/hip_runtime.h>

// Problem constants (match reference)
#define NUM_Q    124
#define TWO_Q    248          // 2*NUM_Q, row width of `batch`
#define MAX_STEP 512
#define TM1      511          // MAX_STEP - 1

// ---------------------------------------------------------------------------
// Kernel 1: for every [b, t] row of `batch` (one-hot * step_mask over 248
// cols), find the index of the hot column, or -1 if the row is all-zero
// (padding). One wave (64 lanes) per row; lanes 0..61 each load one float4
// (62 * 16B = 992B = full row, coalesced), then wave-min-reduce the index.
// ---------------------------------------------------------------------------
__global__ __launch_bounds__(256) void find_cols_kernel(
    const float* __restrict__ batch, int* __restrict__ cols, int nrows)
{
    int gid  = blockIdx.x * 256 + threadIdx.x;
    int row  = gid >> 6;                // one wave per row
    int lane = threadIdx.x & 63;
    if (row >= nrows) return;           // wave-uniform exit

    int cand = 0x7fffffff;
    if (lane < TWO_Q / 4) {             // lanes 0..61 active
        const float4* rp = (const float4*)(batch + (size_t)row * TWO_Q);
        float4 v = rp[lane];
        int base = lane * 4;
        if (v.w >= 1.0f) cand = base + 3;
        if (v.z >= 1.0f) cand = base + 2;
        if (v.y >= 1.0f) cand = base + 1;
        if (v.x >= 1.0f) cand = base;
    }
    #pragma unroll
    for (int off = 32; off > 0; off >>= 1) {
        int o = __shfl_down(cand, off, 64);
        cand = (o < cand) ? o : cand;
    }
    if (lane == 0)
        cols[row] = (cand == 0x7fffffff) ? -1 : cand;
}

// ---------------------------------------------------------------------------
// Kernel 2: one block (256 threads) per student. Each thread owns steps
// t = tid and t = tid+256 (covers t in [0, 511)). Gather p = pred[b,t,q],
// a = (col < NUM_Q). Block-reduce `last` (max t with p>0), then compute
// masked BCE, write p*mask / a*mask, and atomicAdd(sum/L) into out[0].
// ---------------------------------------------------------------------------
__global__ __launch_bounds__(256) void loss_kernel(
    const float* __restrict__ pred, const int* __restrict__ cols,
    float* __restrict__ out, int B)
{
    int b   = blockIdx.x;
    int tid = threadIdx.x;
    const int*   crow = cols + (size_t)b * MAX_STEP;
    const float* prow = pred + (size_t)b * MAX_STEP * NUM_Q;

    int t0 = tid, t1 = tid + 256;
    float p0 = 0.f, p1 = 0.f, a0 = 0.f, a1 = 0.f;
    int local_last = -1;

    {
        int col = crow[t0 + 1];
        if (col >= 0) {
            int q = (col < NUM_Q) ? col : (col - NUM_Q);
            a0 = (col < NUM_Q) ? 1.f : 0.f;
            p0 = prow[(size_t)t0 * NUM_Q + q];
            if (p0 > 0.f) local_last = t0;
        }
    }
    if (t1 < TM1) {
        int col = crow[t1 + 1];
        if (col >= 0) {
            int q = (col < NUM_Q) ? col : (col - NUM_Q);
            a1 = (col < NUM_Q) ? 1.f : 0.f;
            p1 = prow[(size_t)t1 * NUM_Q + q];
            if (p1 > 0.f) local_last = t1;
        }
    }

    // --- block max-reduce of local_last -> last ---
    __shared__ int   s_last[4];
    __shared__ float s_sum[4];
    #pragma unroll
    for (int off = 32; off > 0; off >>= 1) {
        int o = __shfl_down(local_last, off, 64);
        local_last = (o > local_last) ? o : local_last;
    }
    int wid = tid >> 6;
    if ((tid & 63) == 0) s_last[wid] = local_last;
    __syncthreads();
    int last = max(max(s_last[0], s_last[1]), max(s_last[2], s_last[3]));
    int L = (last >= 0) ? (last + 1) : TM1;

    float* out_p = out + 1 + (size_t)b * TM1;
    float* out_a = out + 1 + (size_t)B * TM1 + (size_t)b * TM1;

    float sum = 0.f;
    {
        bool m = (t0 < L);
        out_p[t0] = m ? p0 : 0.f;
        out_a[t0] = m ? a0 : 0.f;
        if (m) {
            float lp  = fmaxf(logf(p0),       -100.f);   // logf(0) = -inf -> clamp
            float l1p = fmaxf(logf(1.f - p0), -100.f);
            sum += -(a0 * lp + (1.f - a0) * l1p);
        }
    }
    if (t1 < TM1) {
        bool m = (t1 < L);
        out_p[t1] = m ? p1 : 0.f;
        out_a[t1] = m ? a1 : 0.f;
        if (m) {
            float lp  = fmaxf(logf(p1),       -100.f);
            float l1p = fmaxf(logf(1.f - p1), -100.f);
            sum += -(a1 * lp + (1.f - a1) * l1p);
        }
    }

    // --- block sum-reduce -> atomicAdd(out[0], sum / L) ---
    #pragma unroll
    for (int off = 32; off > 0; off >>= 1)
        sum += __shfl_down(sum, off, 64);
    if ((tid & 63) == 0) s_sum[wid] = sum;
    __syncthreads();
    if (tid == 0) {
        float tot = s_sum[0] + s_sum[1] + s_sum[2] + s_sum[3];
        atomicAdd(out, tot / (float)L);
    }
}

extern "C" void kernel_launch(void* const* d_in, const int* in_sizes, int n_in,
                              void* d_out, int out_size, void* d_ws, size_t ws_size,
                              hipStream_t stream)
{
    const float* pred  = (const float*)d_in[0];   // [B, 512, 124] f32
    const float* batch = (const float*)d_in[1];   // [B, 512, 248] f32
    float* out = (float*)d_out;                   // [1 + B*511 + B*511] f32
    int*   cols = (int*)d_ws;                     // B*512 ints (4 MB)

    int B = in_sizes[0] / (MAX_STEP * NUM_Q);     // 2048
    int nrows = B * MAX_STEP;

    // out[0] is accumulated with atomics; harness poisons d_out with 0xAA.
    hipMemsetAsync(d_out, 0, sizeof(float), stream);

    // 4 waves per 256-thread block, one wave per row.
    int blocks1 = (nrows + 3) / 4;
    find_cols_kernel<<<blocks1, 256, 0, stream>>>(batch, cols, nrows);

    loss_kernel<<<B, 256, 0, stream>>>(pred, cols, out, B);
}

// Round 2
// 1514.177 us; speedup vs baseline: 1.0005x; 1.0005x over previous
//
#include <hip/hip_runtime.h>

// Problem constants (match reference)
#define NUM_Q    124
#define TWO_Q    248          // 2*NUM_Q, row width of `batch`
#define MAX_STEP 512
#define TM1      511          // MAX_STEP - 1
#define V4_PER_ROW 62         // 248 / 4 float4s per [b,t] row

// ---------------------------------------------------------------------------
// Kernel A: grid-stride scan of `batch` viewed as float4[]. Each [b,t] row is
// one-hot (or all-zero padding), so at most ONE element across the whole row
// is >= 1.0 -> at most one thread writes cols[row]; no race, no reduction.
// cols must be pre-initialized to -1 (memset 0xFF).
// Pure streaming: 16 B/lane coalesced loads, ~1M scattered 4 B stores total.
// ---------------------------------------------------------------------------
__global__ __launch_bounds__(256) void scan_kernel(
    const float4* __restrict__ batch4, int* __restrict__ cols, unsigned n4)
{
    unsigned stride = gridDim.x * 256u;
    for (unsigned i = blockIdx.x * 256u + threadIdx.x; i < n4; i += stride) {
        float4 v = batch4[i];
        if (v.x >= 1.f || v.y >= 1.f || v.z >= 1.f || v.w >= 1.f) {
            unsigned row  = i / V4_PER_ROW;          // magic-mul, no div unit
            unsigned base = (i - row * V4_PER_ROW) * 4u;
            int col = (v.x >= 1.f) ? (int)base
                    : (v.y >= 1.f) ? (int)base + 1
                    : (v.z >= 1.f) ? (int)base + 2
                    : (int)base + 3;
            cols[row] = col;
        }
    }
}

// ---------------------------------------------------------------------------
// Kernel B: one block (256 threads) per student. Each thread owns steps
// t = tid and t = tid+256 (covers t in [0, 511)). Gather p = pred[b,t,q],
// a = (col < NUM_Q). Block-reduce `last` (max t with p>0), then compute
// masked BCE, write p*mask / a*mask, and atomicAdd(sum/L) into out[0].
// ---------------------------------------------------------------------------
__global__ __launch_bounds__(256) void loss_kernel(
    const float* __restrict__ pred, const int* __restrict__ cols,
    float* __restrict__ out, int B)
{
    int b   = blockIdx.x;
    int tid = threadIdx.x;
    const int*   crow = cols + (size_t)b * MAX_STEP;
    const float* prow = pred + (size_t)b * MAX_STEP * NUM_Q;

    int t0 = tid, t1 = tid + 256;
    float p0 = 0.f, p1 = 0.f, a0 = 0.f, a1 = 0.f;
    int local_last = -1;

    {
        int col = crow[t0 + 1];
        if (col >= 0) {
            int q = (col < NUM_Q) ? col : (col - NUM_Q);
            a0 = (col < NUM_Q) ? 1.f : 0.f;
            p0 = prow[(size_t)t0 * NUM_Q + q];
            if (p0 > 0.f) local_last = t0;
        }
    }
    if (t1 < TM1) {
        int col = crow[t1 + 1];
        if (col >= 0) {
            int q = (col < NUM_Q) ? col : (col - NUM_Q);
            a1 = (col < NUM_Q) ? 1.f : 0.f;
            p1 = prow[(size_t)t1 * NUM_Q + q];
            if (p1 > 0.f) local_last = t1;
        }
    }

    // --- block max-reduce of local_last -> last ---
    __shared__ int   s_last[4];
    __shared__ float s_sum[4];
    #pragma unroll
    for (int off = 32; off > 0; off >>= 1) {
        int o = __shfl_down(local_last, off, 64);
        local_last = (o > local_last) ? o : local_last;
    }
    int wid = tid >> 6;
    if ((tid & 63) == 0) s_last[wid] = local_last;
    __syncthreads();
    int last = max(max(s_last[0], s_last[1]), max(s_last[2], s_last[3]));
    int L = (last >= 0) ? (last + 1) : TM1;

    float* out_p = out + 1 + (size_t)b * TM1;
    float* out_a = out + 1 + (size_t)B * TM1 + (size_t)b * TM1;

    float sum = 0.f;
    {
        bool m = (t0 < L);
        out_p[t0] = m ? p0 : 0.f;
        out_a[t0] = m ? a0 : 0.f;
        if (m) {
            float lp  = fmaxf(logf(p0),       -100.f);   // logf(0) = -inf -> clamp
            float l1p = fmaxf(logf(1.f - p0), -100.f);
            sum += -(a0 * lp + (1.f - a0) * l1p);
        }
    }
    if (t1 < TM1) {
        bool m = (t1 < L);
        out_p[t1] = m ? p1 : 0.f;
        out_a[t1] = m ? a1 : 0.f;
        if (m) {
            float lp  = fmaxf(logf(p1),       -100.f);
            float l1p = fmaxf(logf(1.f - p1), -100.f);
            sum += -(a1 * lp + (1.f - a1) * l1p);
        }
    }

    // --- block sum-reduce -> atomicAdd(out[0], sum / L) ---
    #pragma unroll
    for (int off = 32; off > 0; off >>= 1)
        sum += __shfl_down(sum, off, 64);
    if ((tid & 63) == 0) s_sum[wid] = sum;
    __syncthreads();
    if (tid == 0) {
        float tot = s_sum[0] + s_sum[1] + s_sum[2] + s_sum[3];
        atomicAdd(out, tot / (float)L);
    }
}

extern "C" void kernel_launch(void* const* d_in, const int* in_sizes, int n_in,
                              void* d_out, int out_size, void* d_ws, size_t ws_size,
                              hipStream_t stream)
{
    const float* pred  = (const float*)d_in[0];   // [B, 512, 124] f32
    const float* batch = (const float*)d_in[1];   // [B, 512, 248] f32
    float* out = (float*)d_out;                   // [1 + B*511 + B*511] f32
    int*   cols = (int*)d_ws;                     // B*512 ints (4 MB)

    int B = in_sizes[0] / (MAX_STEP * NUM_Q);     // 2048
    int nrows = B * MAX_STEP;
    unsigned n4 = (unsigned)nrows * V4_PER_ROW;   // 65,011,712 float4s

    // cols pre-init to -1 (padding rows are never written by scan_kernel).
    hipMemsetAsync(cols, 0xFF, (size_t)nrows * sizeof(int), stream);
    // out[0] is accumulated with atomics; harness poisons d_out with 0xAA.
    hipMemsetAsync(d_out, 0, sizeof(float), stream);

    // Persistent grid-stride scan: 4096 blocks x 256 threads, 62 iters/thread.
    scan_kernel<<<4096, 256, 0, stream>>>((const float4*)batch, cols, n4);

    loss_kernel<<<B, 256, 0, stream>>>(pred, cols, out, B);
}

// Round 3
// 1497.815 us; speedup vs baseline: 1.0114x; 1.0109x over previous
//
#include <hip/hip_runtime.h>

// Problem constants (match reference)
#define NUM_Q    124
#define TWO_Q    248          // 2*NUM_Q, row width of `batch`
#define MAX_STEP 512
#define TM1      511          // MAX_STEP - 1
#define V4_PER_ROW 62         // 248 / 4 float4s per [b,t] row

// ---------------------------------------------------------------------------
// Fused kernel: one block (256 threads, 4 waves) per student.
//
// Phase 1: wave w scans rows t in [128w, 128w+128) of this student's `batch`
//   slice. Lanes 0..61 each load one float4 (62*16B = 992B = full row,
//   coalesced, rows sequential per wave). Each [b,t] row is one-hot (or all
//   zero padding), so at most ONE lane sees a hot element -> it scatters the
//   column index into LDS scols[t]; no reduction, no race.
//
// Phase 2: per-step gather p = pred[b,t, col%124], a = (col<124); block-max
//   of last (t with p>0) -> L; masked BCE; write p*mask / a*mask; one
//   atomicAdd(sum/L) per block into out[0] (zeroed via hipMemsetAsync).
// ---------------------------------------------------------------------------
__global__ __launch_bounds__(256) void fused_loss_kernel(
    const float* __restrict__ pred, const float* __restrict__ batch,
    float* __restrict__ out, int B)
{
    __shared__ int   scols[MAX_STEP];
    __shared__ int   s_last[4];
    __shared__ float s_sum[4];

    int b    = blockIdx.x;
    int tid  = threadIdx.x;
    int wid  = tid >> 6;
    int lane = tid & 63;

    scols[tid]       = -1;
    scols[tid + 256] = -1;
    __syncthreads();

    // ---- Phase 1: scan batch rows, scatter hot column into LDS ----
    const float4* brow4 = (const float4*)(batch + (size_t)b * MAX_STEP * TWO_Q);
    if (lane < V4_PER_ROW) {
        int base = lane * 4;
        #pragma unroll 4
        for (int i = 0; i < 128; ++i) {
            int t = wid * 128 + i;
            float4 v = brow4[(size_t)t * V4_PER_ROW + lane];
            if (v.x >= 1.f || v.y >= 1.f || v.z >= 1.f || v.w >= 1.f) {
                int col = (v.x >= 1.f) ? base
                        : (v.y >= 1.f) ? base + 1
                        : (v.z >= 1.f) ? base + 2
                        : base + 3;
                scols[t] = col;
            }
        }
    }
    __syncthreads();

    // ---- Phase 2: gather pred, compute masked BCE ----
    const float* prow = pred + (size_t)b * MAX_STEP * NUM_Q;
    int t0 = tid, t1 = tid + 256;
    float p0 = 0.f, p1 = 0.f, a0 = 0.f, a1 = 0.f;
    int local_last = -1;

    {
        int col = scols[t0 + 1];
        if (col >= 0) {
            int q = (col < NUM_Q) ? col : (col - NUM_Q);
            a0 = (col < NUM_Q) ? 1.f : 0.f;
            p0 = prow[(size_t)t0 * NUM_Q + q];
            if (p0 > 0.f) local_last = t0;
        }
    }
    if (t1 < TM1) {
        int col = scols[t1 + 1];
        if (col >= 0) {
            int q = (col < NUM_Q) ? col : (col - NUM_Q);
            a1 = (col < NUM_Q) ? 1.f : 0.f;
            p1 = prow[(size_t)t1 * NUM_Q + q];
            if (p1 > 0.f) local_last = t1;
        }
    }

    // block max-reduce of local_last -> last
    #pragma unroll
    for (int off = 32; off > 0; off >>= 1) {
        int o = __shfl_down(local_last, off, 64);
        local_last = (o > local_last) ? o : local_last;
    }
    if (lane == 0) s_last[wid] = local_last;
    __syncthreads();
    int last = max(max(s_last[0], s_last[1]), max(s_last[2], s_last[3]));
    int L = (last >= 0) ? (last + 1) : TM1;

    float* out_p = out + 1 + (size_t)b * TM1;
    float* out_a = out + 1 + (size_t)B * TM1 + (size_t)b * TM1;

    float sum = 0.f;
    {
        bool m = (t0 < L);
        out_p[t0] = m ? p0 : 0.f;
        out_a[t0] = m ? a0 : 0.f;
        if (m) {
            float lp  = fmaxf(logf(p0),       -100.f);   // logf(0)=-inf -> clamp
            float l1p = fmaxf(logf(1.f - p0), -100.f);
            sum += -(a0 * lp + (1.f - a0) * l1p);
        }
    }
    if (t1 < TM1) {
        bool m = (t1 < L);
        out_p[t1] = m ? p1 : 0.f;
        out_a[t1] = m ? a1 : 0.f;
        if (m) {
            float lp  = fmaxf(logf(p1),       -100.f);
            float l1p = fmaxf(logf(1.f - p1), -100.f);
            sum += -(a1 * lp + (1.f - a1) * l1p);
        }
    }

    // block sum-reduce -> one atomicAdd per student
    #pragma unroll
    for (int off = 32; off > 0; off >>= 1)
        sum += __shfl_down(sum, off, 64);
    if (lane == 0) s_sum[wid] = sum;
    __syncthreads();
    if (tid == 0) {
        float tot = s_sum[0] + s_sum[1] + s_sum[2] + s_sum[3];
        atomicAdd(out, tot / (float)L);
    }
}

extern "C" void kernel_launch(void* const* d_in, const int* in_sizes, int n_in,
                              void* d_out, int out_size, void* d_ws, size_t ws_size,
                              hipStream_t stream)
{
    const float* pred  = (const float*)d_in[0];   // [B, 512, 124] f32
    const float* batch = (const float*)d_in[1];   // [B, 512, 248] f32
    float* out = (float*)d_out;                   // [1 + B*511 + B*511] f32

    int B = in_sizes[0] / (MAX_STEP * NUM_Q);     // 2048

    // out[0] is accumulated with atomics; harness poisons d_out with 0xAA.
    hipMemsetAsync(d_out, 0, sizeof(float), stream);

    fused_loss_kernel<<<B, 256, 0, stream>>>(pred, batch, out, B);
}